// Round 10
// baseline (479.893 us; speedup 1.0000x reference)
//
#include <hip/hip_runtime.h>
#include <hip/hip_bf16.h>
#include <math.h>

#define NN 100000
#define NCLS 40
#define DEGC 16
#define NEDGE (NN*DEGC)
#define ALPHAC 0.2f
#define LPALPHA 0.5f

typedef short short8v __attribute__((ext_vector_type(8)));
typedef float f32x4 __attribute__((ext_vector_type(4)));

__device__ __forceinline__ short f2bf(float f) {
    unsigned u = __float_as_uint(f);
    u += 0x7fff + ((u >> 16) & 1);           // round-to-nearest-even
    return (short)(u >> 16);
}
__device__ __forceinline__ float bf2f(ushort u) {
    return __uint_as_float(((unsigned)u) << 16);
}

// ---------------------------------------------------------------------------
// MFMA GEMM (LDS-staged B).  CSLICE: C written slice-major [8][NN][16]
// (slice = n-tile index) for the XCD-affine aggregation gather.
// ---------------------------------------------------------------------------
template <int NCH1, bool ABF, bool HASL, bool CSLICE>
__global__ __launch_bounds__(256) void gemm128_lds(
    const void* __restrict__ A1v, const ushort* __restrict__ B1t,
    const ushort* __restrict__ labB64, const ushort* __restrict__ B2t,
    const float* __restrict__ bias, int leakyA, ushort* __restrict__ C)
{
    constexpr int K1 = NCH1 * 32;
    constexpr int NG = NCH1 / 4;
    constexpr int NCH = NCH1 + (HASL ? 2 : 0);
    __shared__ __align__(16) ushort Bs1[128 * 128];
    __shared__ __align__(16) ushort Bs2[HASL ? 128 * 64 : 8];

    const int tid = threadIdx.x;
    const int l   = tid & 63;
    const int w   = tid >> 6;
    const int lr  = l & 15;
    const int lk8 = (l >> 4) << 3;
    const int n0  = blockIdx.x * 64 + w * 16;
    int r = n0 + lr; r = r < NN ? r : NN - 1;
    const int swz = (lr & 7) << 4;

    short8v afr[NCH];
    if (ABF) {
        const ushort* __restrict__ A = (const ushort*)A1v;
#pragma unroll
        for (int kc = 0; kc < NCH1; ++kc)
            afr[kc] = *(const short8v*)(A + (size_t)r * K1 + kc * 32 + lk8);
    } else {
        const float* __restrict__ A = (const float*)A1v;
#pragma unroll
        for (int g = 0; g < NCH1; g += 2) {
            const float* p0 = A + (size_t)r * K1 + g * 32 + lk8;
            const float* p1 = A + (size_t)r * K1 + (g + 1) * 32 + lk8;
            float4 a0 = *(const float4*)p0;
            float4 a1 = *(const float4*)(p0 + 4);
            float4 b0 = *(const float4*)p1;
            float4 b1 = *(const float4*)(p1 + 4);
            short8v va, vb;
            va[0] = f2bf(a0.x); va[1] = f2bf(a0.y); va[2] = f2bf(a0.z); va[3] = f2bf(a0.w);
            va[4] = f2bf(a1.x); va[5] = f2bf(a1.y); va[6] = f2bf(a1.z); va[7] = f2bf(a1.w);
            vb[0] = f2bf(b0.x); vb[1] = f2bf(b0.y); vb[2] = f2bf(b0.z); vb[3] = f2bf(b0.w);
            vb[4] = f2bf(b1.x); vb[5] = f2bf(b1.y); vb[6] = f2bf(b1.z); vb[7] = f2bf(b1.w);
            afr[g] = va;
            afr[g + 1] = vb;
        }
    }
    if (HASL) {
        afr[NCH1]     = *(const short8v*)(labB64 + (size_t)r * 64 + lk8);
        afr[NCH1 + 1] = *(const short8v*)(labB64 + (size_t)r * 64 + 32 + lk8);
    }
    if (ABF && leakyA) {
#pragma unroll
        for (int kc = 0; kc < NCH1; ++kc)
#pragma unroll
            for (int j = 0; j < 8; ++j) {
                float f = bf2f((ushort)afr[kc][j]);
                f = f > 0.f ? f : ALPHAC * f;
                afr[kc][j] = f2bf(f);
            }
    }

    if (HASL) {
#pragma unroll
        for (int s = 0; s < 4; ++s) {
            const int slot = tid + s * 256;
            const int row = slot >> 3, colq = slot & 7;
            uint4 v = *(const uint4*)(B2t + (size_t)row * 64 + colq * 8);
            *(uint4*)((char*)Bs2 + ((row * 128 + colq * 16) ^ ((row & 7) << 4))) = v;
        }
    }

    f32x4 acc[8];
#pragma unroll
    for (int ni = 0; ni < 8; ++ni) acc[ni] = (f32x4){0.f, 0.f, 0.f, 0.f};

#pragma unroll
    for (int g = 0; g < NG; ++g) {
        if (g) __syncthreads();
#pragma unroll
        for (int s = 0; s < 8; ++s) {
            const int slot = tid + s * 256;
            const int row = slot >> 4, colq = slot & 15;
            uint4 v = *(const uint4*)(B1t + (size_t)row * K1 + g * 128 + colq * 8);
            *(uint4*)((char*)Bs1 + ((row * 256 + colq * 16) ^ ((row & 7) << 4))) = v;
        }
        __syncthreads();
#pragma unroll
        for (int ni = 0; ni < 8; ++ni) {
#pragma unroll
            for (int kc = 0; kc < 4; ++kc) {
                short8v b = *(const short8v*)((const char*)Bs1 +
                    (((ni * 16 + lr) * 256 + kc * 64 + lk8 * 2) ^ swz));
                acc[ni] = __builtin_amdgcn_mfma_f32_16x16x32_bf16(afr[g * 4 + kc], b, acc[ni], 0, 0, 0);
            }
        }
    }
    if (HASL) {
#pragma unroll
        for (int ni = 0; ni < 8; ++ni) {
#pragma unroll
            for (int kc = 0; kc < 2; ++kc) {
                short8v b = *(const short8v*)((const char*)Bs2 +
                    (((ni * 16 + lr) * 128 + kc * 64 + lk8 * 2) ^ swz));
                acc[ni] = __builtin_amdgcn_mfma_f32_16x16x32_bf16(afr[NCH1 + kc], b, acc[ni], 0, 0, 0);
            }
        }
    }

    const int rsub = (l >> 4) << 2;
#pragma unroll
    for (int ni = 0; ni < 8; ++ni) {
        const int cc = ni * 16 + lr;
        const float bv = bias ? bias[cc] : 0.f;
#pragma unroll
        for (int rg = 0; rg < 4; ++rg) {
            const int rr = n0 + rsub + rg;
            if (rr < NN) {
                const ushort ov = (ushort)f2bf(acc[ni][rg] + bv);
                if (CSLICE) C[(size_t)ni * (NN * 16) + (size_t)rr * 16 + lr] = ov;
                else        C[(size_t)rr * 128 + cc] = ov;
            }
        }
    }
}

// ---------------------------------------------------------------------------
// XCD-affine aggregation.  Table is slice-major [8][NN][16]; slice = bid & 7
// so all blocks of one slice land on one XCD (round-robin dispatch) and its
// 3.2 MB slice stays L2-resident.  Output row-major via nontemporal stores.
// 8 lanes per node (2 cols/lane); 32 nodes/block.
// ---------------------------------------------------------------------------
__global__ __launch_bounds__(256) void agg_xcd(
    const ushort* __restrict__ tab, const int* __restrict__ col,
    const float* __restrict__ sd, const float* __restrict__ degree,
    const float* __restrict__ aggrv, const float aggrs, int do_leaky,
    ushort* __restrict__ hout)
{
    __shared__ int   cs[32 * 17];
    __shared__ float ss[32 * 17];
    const int slice = blockIdx.x & 7;
    const int nb    = blockIdx.x >> 3;
    const int tid   = threadIdx.x;
    const int base  = nb * 32;
#pragma unroll
    for (int s = 0; s < 2; ++s) {
        const int idx = tid + s * 256;       // 0..511
        const int nl = idx >> 4, t = idx & 15;
        const int c = col[(size_t)(base + nl) * 16 + t];
        cs[nl * 17 + t] = c;
        ss[nl * 17 + t] = sd[c];
    }
    __syncthreads();
    const int l  = tid & 63;
    const int g  = l >> 3, li = l & 7;
    const int nl = (tid >> 6) * 8 + g;
    const int node = base + nl;
    const ushort* __restrict__ ts = tab + (size_t)slice * (NN * 16);
    float ax = 0.f, ay = 0.f;
#pragma unroll
    for (int t = 0; t < 16; ++t) {
        const int   c  = cs[nl * 17 + t];
        const float wv = ss[nl * 17 + t];
        const unsigned u = *(const unsigned*)(ts + (size_t)c * 16 + li * 2);
        ax += wv * bf2f((ushort)(u & 0xffff));
        ay += wv * bf2f((ushort)(u >> 16));
    }
    const unsigned us = *(const unsigned*)(ts + (size_t)node * 16 + li * 2);
    const float a = aggrv ? aggrv[node] : aggrs;
    const float d = degree[node];
    float ox = a * ax * d + (1.f - a) * bf2f((ushort)(us & 0xffff));
    float oy = a * ay * d + (1.f - a) * bf2f((ushort)(us >> 16));
    if (do_leaky) {
        ox = ox > 0.f ? ox : ALPHAC * ox;
        oy = oy > 0.f ? oy : ALPHAC * oy;
    }
    const unsigned uo = (unsigned)(ushort)f2bf(ox) | ((unsigned)(ushort)f2bf(oy) << 16);
    __builtin_nontemporal_store(uo,
        (unsigned*)(hout + (size_t)node * 128 + slice * 16 + li * 2));
}

__global__ void prep_sd(const float* __restrict__ lpw, const float* __restrict__ degree,
                        float* __restrict__ sd)
{
    int i = blockIdx.x * 256 + threadIdx.x;
    if (i < NN) sd[i] = lpw[i] * degree[i];
}

// ---------------------------------------------------------------------------
// Small MFMA GEMM (LDS-staged W) writing packed Mb01[N][32] (m0@0, m1@16).
// ---------------------------------------------------------------------------
__global__ __launch_bounds__(256) void gemm16_mfma(
    const ushort* __restrict__ A, const ushort* __restrict__ Wb,
    const float* __restrict__ bias, ushort* __restrict__ Mout, int ooff)
{
    __shared__ __align__(16) ushort Wl[16 * 128];
    const int tid = threadIdx.x;
    const int l  = tid & 63;
    const int w  = tid >> 6;
    const int lr = l & 15;
    const int lk = (l >> 4) << 3;
    const int swz = (lr & 7) << 4;
    {
        const int row = tid >> 4, colq = tid & 15;
        uint4 v = *(const uint4*)(Wb + (size_t)row * 128 + colq * 8);
        *(uint4*)((char*)Wl + ((row * 256 + colq * 16) ^ ((row & 7) << 4))) = v;
    }
    const int n0 = blockIdx.x * 64 + w * 16;
    int ar = n0 + lr; ar = ar < NN ? ar : NN - 1;
    short8v a[4];
#pragma unroll
    for (int kc = 0; kc < 4; ++kc)
        a[kc] = *(const short8v*)(A + (size_t)ar * 128 + kc * 32 + lk);
    __syncthreads();
    f32x4 acc = (f32x4){0.f, 0.f, 0.f, 0.f};
#pragma unroll
    for (int kc = 0; kc < 4; ++kc) {
        short8v b = *(const short8v*)((const char*)Wl + ((lr * 256 + kc * 64 + lk * 2) ^ swz));
        acc = __builtin_amdgcn_mfma_f32_16x16x32_bf16(a[kc], b, acc, 0, 0, 0);
    }
    const float bv = bias[lr];
    const int rb = n0 + ((l >> 4) << 2);
#pragma unroll
    for (int r = 0; r < 4; ++r) {
        int rr = rb + r;
        if (rr < NN) Mout[(size_t)rr * 32 + ooff + lr] = (ushort)f2bf(acc[r] + bv);
    }
}

// ---------------------------------------------------------------------------
// Fused dual mini(): one 64 B gather serves both m0 and m1 distances.
// ---------------------------------------------------------------------------
__global__ __launch_bounds__(256) void mini2_dual(
    const ushort* __restrict__ Mb01, const int* __restrict__ col,
    float* __restrict__ d2_0, float* __restrict__ d2_1)
{
    __shared__ float sm0[16][16][17];
    __shared__ float sm1[16][16][17];
    __shared__ float av0[16][16];
    __shared__ float av1[16][16];
    const int tid = threadIdx.x;
    const int g = tid >> 4, j = tid & 15;
    const int node = blockIdx.x * 16 + g;
    const int c = col[node * 16 + j];
    const ushort* __restrict__ rowp = Mb01 + (size_t)c * 32;
    const uint4 u0 = *(const uint4*)rowp;
    const uint4 u1 = *(const uint4*)(rowp + 8);
    const uint4 u2 = *(const uint4*)(rowp + 16);
    const uint4 u3 = *(const uint4*)(rowp + 24);
    const unsigned w0[8] = {u0.x, u0.y, u0.z, u0.w, u1.x, u1.y, u1.z, u1.w};
    const unsigned w1[8] = {u2.x, u2.y, u2.z, u2.w, u3.x, u3.y, u3.z, u3.w};
#pragma unroll
    for (int s = 0; s < 8; ++s) {
        sm0[g][j][s * 2]     = bf2f((ushort)(w0[s] & 0xffff));
        sm0[g][j][s * 2 + 1] = bf2f((ushort)(w0[s] >> 16));
        sm1[g][j][s * 2]     = bf2f((ushort)(w1[s] & 0xffff));
        sm1[g][j][s * 2 + 1] = bf2f((ushort)(w1[s] >> 16));
    }
    __syncthreads();
    float a0 = 0.f, a1 = 0.f;
#pragma unroll
    for (int nb = 0; nb < 16; ++nb) { a0 += sm0[g][nb][j]; a1 += sm1[g][nb][j]; }
    av0[g][j] = a0 * (1.f / 16.f);
    av1[g][j] = a1 * (1.f / 16.f);
    __syncthreads();
    float dd0 = 1e-12f, dd1 = 1e-12f;
#pragma unroll
    for (int d = 0; d < 16; ++d) {
        float t0 = av0[g][d] - sm0[g][j][d];
        float t1 = av1[g][d] - sm1[g][j][d];
        dd0 += t0 * t0;
        dd1 += t1 * t1;
    }
    float dist0 = sqrtf(dd0), dist1 = sqrtf(dd1);
#pragma unroll
    for (int off = 1; off < 16; off <<= 1) {
        dist0 += __shfl_xor(dist0, off, 64);
        dist1 += __shfl_xor(dist1, off, 64);
    }
    if (j == 0) {
        d2_0[node] = dist0 * (1.f / 16.f);
        d2_1[node] = dist1 * (1.f / 16.f);
    }
}

// ---------------------------------------------------------------------------
// Per-node factor precompute (reads packed Mb01).
// ---------------------------------------------------------------------------
__global__ __launch_bounds__(256) void prep_pnode(
    const ushort* __restrict__ Mb01, const float* __restrict__ d2_0,
    const float* __restrict__ d2_1,
    const float* __restrict__ ab, const float* __restrict__ lf1w,
    const float* __restrict__ lf1b,
    float* __restrict__ P0s, float* __restrict__ P1s, ushort* __restrict__ PD)
{
    const int idx = blockIdx.x * 256 + threadIdx.x;
    const int i = idx >> 4, k = idx & 15;
    float m0[17], m1a[17];
    const ushort* r0 = Mb01 + (size_t)i * 32;
    const ushort* r1 = r0 + 16;
#pragma unroll
    for (int d = 0; d < 16; ++d) {
        m0[d]  = bf2f(r0[d]);
        m1a[d] = bf2f(r1[d]) + ab[d];
    }
    m0[16]  = d2_0[i];
    m1a[16] = d2_1[i] + ab[16];
    const float* __restrict__ Wk = lf1w + k * 51;
    float p0s = lf1b[k], p1s = p0s, p0d = 0.f, p1d = 0.f;
#pragma unroll
    for (int d = 0; d < 17; ++d) {
        const float w0 = Wk[d], w1 = Wk[17 + d];
        p0s += m0[d]  * w0;  p0d += m0[d]  * w1;
        p1s += m1a[d] * w0;  p1d += m1a[d] * w1;
    }
    P0s[idx] = p0s;
    P1s[idx] = p1s;
    PD[(size_t)i * 32 + k]      = (ushort)f2bf(p0d);
    PD[(size_t)i * 32 + 16 + k] = (ushort)f2bf(p1d);
}

// ---------------------------------------------------------------------------
// Edge factors (m0 from packed Mb01, stride 32); fused f1hop.
// ---------------------------------------------------------------------------
__global__ __launch_bounds__(256) void fact2_kernel(
    const ushort* __restrict__ Mb01, const float* __restrict__ d2_0,
    const float* __restrict__ P0s, const float* __restrict__ P1s,
    const ushort* __restrict__ PD, const int* __restrict__ col,
    const float* __restrict__ W2c, const float* __restrict__ lf2w,
    const float* __restrict__ lf2b,
    float* __restrict__ f0out, float* __restrict__ f1hout)
{
    const int e = blockIdx.x * 256 + threadIdx.x;
    const int i = e >> 4;
    const int c = col[e];

    const uint4 ui0 = *(const uint4*)(Mb01 + (size_t)i * 32);
    const uint4 ui1 = *(const uint4*)(Mb01 + (size_t)i * 32 + 8);
    const uint4 uc0 = *(const uint4*)(Mb01 + (size_t)c * 32);
    const uint4 uc1 = *(const uint4*)(Mb01 + (size_t)c * 32 + 8);
    const unsigned wi[8] = {ui0.x, ui0.y, ui0.z, ui0.w, ui1.x, ui1.y, ui1.z, ui1.w};
    const unsigned wc[8] = {uc0.x, uc0.y, uc0.z, uc0.w, uc1.x, uc1.y, uc1.z, uc1.w};

    float H[16];
#pragma unroll
    for (int k = 0; k < 16; ++k) H[k] = 0.f;
#pragma unroll
    for (int s = 0; s < 8; ++s) {
        const float hd0 = fabsf(bf2f((ushort)(wc[s] & 0xffff)) - bf2f((ushort)(wi[s] & 0xffff)));
        const float hd1 = fabsf(bf2f((ushort)(wc[s] >> 16))    - bf2f((ushort)(wi[s] >> 16)));
        const float* __restrict__ w0 = W2c + (s * 2) * 16;
        const float* __restrict__ w1 = W2c + (s * 2 + 1) * 16;
#pragma unroll
        for (int k = 0; k < 16; ++k) H[k] += hd0 * w0[k] + hd1 * w1[k];
    }
    {
        const float hdd = fabsf(d2_0[c] - d2_0[i]);
        const float* __restrict__ w = W2c + 16 * 16;
#pragma unroll
        for (int k = 0; k < 16; ++k) H[k] += hdd * w[k];
    }

    const float* __restrict__ p0 = P0s + (size_t)i * 16;
    const float* __restrict__ p1 = P1s + (size_t)i * 16;
    const ushort* __restrict__ pd = PD + (size_t)c * 32;
    const uint4 pd0 = *(const uint4*)pd;
    const uint4 pd1 = *(const uint4*)(pd + 8);
    const uint4 pd2 = *(const uint4*)(pd + 16);
    const uint4 pd3 = *(const uint4*)(pd + 24);
    const unsigned pdu[16] = {pd0.x, pd0.y, pd0.z, pd0.w, pd1.x, pd1.y, pd1.z, pd1.w,
                              pd2.x, pd2.y, pd2.z, pd2.w, pd3.x, pd3.y, pd3.z, pd3.w};
    float P0d[16], P1d[16];
#pragma unroll
    for (int s = 0; s < 8; ++s) {
        P0d[s * 2]     = bf2f((ushort)(pdu[s] & 0xffff));
        P0d[s * 2 + 1] = bf2f((ushort)(pdu[s] >> 16));
        P1d[s * 2]     = bf2f((ushort)(pdu[8 + s] & 0xffff));
        P1d[s * 2 + 1] = bf2f((ushort)(pdu[8 + s] >> 16));
    }
    float a0 = lf2b[0], a1 = a0;
#pragma unroll
    for (int k = 0; k < 16; ++k) {
        const float t0 = p0[k] + P0d[k] + H[k];
        const float t1 = p1[k] + P1d[k] + H[k];
        const float lw = lf2w[k];
        a0 += (1.f - 2.f / (__expf(2.f * t0) + 1.f)) * lw;
        a1 += (1.f - 2.f / (__expf(2.f * t1) + 1.f)) * lw;
    }
    f0out[e] = 1.f / (1.f + __expf(-a0));
    float f1 = 1.f / (1.f + __expf(-a1));
#pragma unroll
    for (int off = 1; off < 16; off <<= 1) f1 += __shfl_xor(f1, off, 64);
    if ((threadIdx.x & 15) == 0) f1hout[i] = f1 * (1.f / 16.f);
}

__global__ void f2hop_kernel(const float* __restrict__ f0, const float* __restrict__ f1h,
                             const int* __restrict__ col, float* __restrict__ out)
{
    const int i = blockIdx.x * 256 + threadIdx.x;
    if (i >= NN) return;
    float s = 0.f;
#pragma unroll
    for (int t = 0; t < 16; ++t) {
        int e = i * 16 + t;
        s += f0[e] * f1h[col[e]];
    }
    out[i] = s * (1.f / 16.f);
}

// ---------------------------------------------------------------------------
// MFMA logits + fused log_softmax (LDS-staged W).
// ---------------------------------------------------------------------------
__global__ __launch_bounds__(256) void logits_mfma(
    const ushort* __restrict__ X, const ushort* __restrict__ Wb48,
    const float* __restrict__ bias, float* __restrict__ out)
{
    __shared__ __align__(16) ushort Wl[48 * 128];
    const int tid = threadIdx.x;
    const int l  = tid & 63;
    const int w  = tid >> 6;
    const int lr = l & 15;
    const int lk = (l >> 4) << 3;
    const int swz = (lr & 7) << 4;
#pragma unroll
    for (int s = 0; s < 6; ++s) {
        const int slot = tid + s * 256;
        const int row = slot >> 4, colq = slot & 15;
        uint4 v = *(const uint4*)(Wb48 + (size_t)row * 128 + colq * 8);
        *(uint4*)((char*)Wl + ((row * 256 + colq * 16) ^ ((row & 7) << 4))) = v;
    }
    const int row_base = blockIdx.x * 128 + w * 32;
    short8v afr[2][4];
#pragma unroll
    for (int mi = 0; mi < 2; ++mi) {
        int r = row_base + mi * 16 + lr;
        r = r < NN ? r : NN - 1;
#pragma unroll
        for (int kc = 0; kc < 4; ++kc)
            afr[mi][kc] = *(const short8v*)(X + (size_t)r * 128 + kc * 32 + lk);
    }
    __syncthreads();
    f32x4 acc[2][3];
#pragma unroll
    for (int mi = 0; mi < 2; ++mi)
#pragma unroll
        for (int ni = 0; ni < 3; ++ni) acc[mi][ni] = (f32x4){0.f, 0.f, 0.f, 0.f};
#pragma unroll
    for (int ni = 0; ni < 3; ++ni) {
#pragma unroll
        for (int kc = 0; kc < 4; ++kc) {
            short8v b = *(const short8v*)((const char*)Wl +
                (((ni * 16 + lr) * 256 + kc * 64 + lk * 2) ^ swz));
#pragma unroll
            for (int mi = 0; mi < 2; ++mi)
                acc[mi][ni] = __builtin_amdgcn_mfma_f32_16x16x32_bf16(afr[mi][kc], b, acc[mi][ni], 0, 0, 0);
        }
    }

    const float b0 = bias[lr];
    const float b1 = bias[16 + lr];
    const float b2 = (lr < 8) ? bias[32 + lr] : 0.f;
    const int rsub = (l >> 4) << 2;
#pragma unroll
    for (int mi = 0; mi < 2; ++mi) {
#pragma unroll
        for (int reg = 0; reg < 4; ++reg) {
            const int row = row_base + mi * 16 + rsub + reg;
            const float z0 = acc[mi][0][reg] + b0;
            const float z1 = acc[mi][1][reg] + b1;
            const float z2 = (lr < 8) ? acc[mi][2][reg] + b2 : -1e30f;
            float m = fmaxf(fmaxf(z0, z1), z2);
#pragma unroll
            for (int off = 1; off < 16; off <<= 1) m = fmaxf(m, __shfl_xor(m, off, 64));
            float s = __expf(z0 - m) + __expf(z1 - m) + ((lr < 8) ? __expf(z2 - m) : 0.f);
#pragma unroll
            for (int off = 1; off < 16; off <<= 1) s += __shfl_xor(s, off, 64);
            const float lg = m + __logf(s);
            if (row < NN) {
                float* __restrict__ po = out + (size_t)row * NCLS;
                po[lr] = z0 - lg;
                po[16 + lr] = z1 - lg;
                if (lr < 8) po[32 + lr] = z2 - lg;
            }
        }
    }
}

// ---------------------------------------------------------------------------
// Prep kernels
// ---------------------------------------------------------------------------
__global__ void cvt_bf16(const float* __restrict__ src, ushort* __restrict__ dst, int n)
{
    int i = blockIdx.x * 256 + threadIdx.x;
    if (i < n) dst[i] = (ushort)f2bf(src[i]);
}

__global__ void cvt_label64(const float* __restrict__ label, ushort* __restrict__ labB64)
{
    int idx = blockIdx.x * 256 + threadIdx.x;
    int i = idx >> 6, c = idx & 63;
    labB64[idx] = (c < NCLS) ? (ushort)f2bf(label[(size_t)i * NCLS + c]) : (ushort)0;
}

__global__ void prep_wt1(const float* __restrict__ Ws, ushort* __restrict__ Wt1)
{
    int i = blockIdx.x * 256 + threadIdx.x;
    int ll = i >> 14, r = i & 16383;
    int m = r >> 7, k = r & 127;
    Wt1[i] = (ushort)f2bf(Ws[(size_t)ll * 32768 + k * 128 + m]);
}

__global__ void prep_w2t(const float* __restrict__ L2F, const float* __restrict__ Ws,
                         ushort* __restrict__ W2t)
{
    int i = blockIdx.x * 256 + threadIdx.x;
    int ll = i >> 13, r = i & 8191;
    int m = r >> 6, c = r & 63;
    float acc = 0.f;
    if (c < NCLS) {
        const float* Wl = Ws + (size_t)ll * 32768 + 128 * 128;
        for (int j = 0; j < 128; ++j) acc += L2F[c * 128 + j] * Wl[j * 128 + m];
    }
    W2t[i] = (ushort)f2bf(acc);
}

__global__ void prep_wb48(const float* __restrict__ la2w, ushort* __restrict__ Wb48)
{
    int i = blockIdx.x * 256 + threadIdx.x;
    if (i >= 48 * 128) return;
    int c = i >> 7;
    Wb48[i] = (c < NCLS) ? (ushort)f2bf(la2w[i]) : (ushort)0;
}

__global__ void prep_w2c(const float* __restrict__ lf1w, float* __restrict__ W2c)
{
    int t = blockIdx.x * 256 + threadIdx.x;
    if (t < 272) {
        int d = t >> 4, k = t & 15;
        W2c[t] = lf1w[k * 51 + 34 + d];
    }
}

// ---------------------------------------------------------------------------
extern "C" void kernel_launch(void* const* d_in, const int* in_sizes, int n_in,
                              void* d_out, int out_size, void* d_ws, size_t ws_size,
                              hipStream_t stream)
{
    const float* x      = (const float*)d_in[0];
    const int*   edges  = (const int*)d_in[1];
    const float* degree = (const float*)d_in[2];
    const float* label  = (const float*)d_in[4];
    const float* lb_w   = (const float*)d_in[5];
    const float* lb_b   = (const float*)d_in[6];
    const float* L2F    = (const float*)d_in[7];
    const float* Ws     = (const float*)d_in[8];
    const float* w2m    = (const float*)d_in[9];
    const float* b2m    = (const float*)d_in[10];
    const float* ab     = (const float*)d_in[11];
    const float* lf1w   = (const float*)d_in[12];
    const float* lf1b   = (const float*)d_in[13];
    const float* lf2w   = (const float*)d_in[14];
    const float* lf2b   = (const float*)d_in[15];
    const float* LPW    = (const float*)d_in[16];
    const float* la2w   = (const float*)d_in[17];
    const float* la2b   = (const float*)d_in[18];
    const int* colp = edges + NEDGE;

    float* ws = (float*)d_ws;
    size_t o = 0;
    float* d2_0B = ws + o; o += NN;
    float* d2_1B = ws + o; o += NN;
    float* P0sB  = ws + o; o += (size_t)NN * 16;
    float* P1sB  = ws + o; o += (size_t)NN * 16;
    float* f0B   = ws + o; o += NEDGE;
    float* f1hB  = ws + o; o += NN;
    float* aggrB = ws + o; o += NN;
    float* sdB   = ws + o; o += NN;
    float* W2cB  = ws + o; o += 272;
    ushort* bufA = (ushort*)(ws + o); o += (size_t)NN * 128 / 2;
    ushort* bufL = (ushort*)(ws + o); o += (size_t)NN * 128 / 2;   // slice-major [8][NN][16]
    ushort* labB64 = (ushort*)(ws + o); o += (size_t)NN * 64 / 2;
    ushort* Mb01 = (ushort*)(ws + o); o += (size_t)NN * 32 / 2;
    ushort* PDB  = (ushort*)(ws + o); o += (size_t)NN * 32 / 2;
    ushort* Bt0  = (ushort*)(ws + o); o += 128 * 256 / 2;
    ushort* Wt1  = (ushort*)(ws + o); o += 2 * 128 * 128 / 2;
    ushort* W2t  = (ushort*)(ws + o); o += 2 * 128 * 64 / 2;
    ushort* W2mB = (ushort*)(ws + o); o += 16 * 128 / 2;
    ushort* Wb48 = (ushort*)(ws + o); o += 48 * 128 / 2;

    dim3 b256(256);
    // prep
    cvt_bf16<<<128, b256, 0, stream>>>(lb_w, Bt0, 128 * 256);
    prep_wt1<<<128, b256, 0, stream>>>(Ws, Wt1);
    prep_w2t<<<64, b256, 0, stream>>>(L2F, Ws, W2t);
    prep_wb48<<<24, b256, 0, stream>>>(la2w, Wb48);
    prep_w2c<<<2, b256, 0, stream>>>(lf1w, W2cB);
    cvt_bf16<<<8, b256, 0, stream>>>(w2m, W2mB, 16 * 128);
    cvt_label64<<<25000, b256, 0, stream>>>(label, labB64);

    // h0 = x @ lb_w^T + lb_b   (A f32, K=256, row-major C)
    gemm128_lds<8, false, false, false><<<1563, b256, 0, stream>>>(x, Bt0, nullptr, nullptr,
                                                                   lb_b, 0, bufA);

    // ---- layer 0 ----
    gemm128_lds<4, true, true, true><<<1563, b256, 0, stream>>>(bufA, Wt1, labB64, W2t,
                                                                nullptr, 0, bufL);
    gemm16_mfma<<<1563, b256, 0, stream>>>(bufA, W2mB, b2m, Mb01, 16);   // m1 = mini(h0)
    prep_sd<<<391, b256, 0, stream>>>(LPW, degree, sdB);
    agg_xcd<<<25000, b256, 0, stream>>>(bufL, colp, sdB, degree,
                                        nullptr, LPALPHA, 0, bufA);
    gemm16_mfma<<<1563, b256, 0, stream>>>(bufA, W2mB, b2m, Mb01, 0);    // m0 = mini(h)
    mini2_dual<<<6250, b256, 0, stream>>>(Mb01, colp, d2_0B, d2_1B);
    prep_pnode<<<6250, b256, 0, stream>>>(Mb01, d2_0B, d2_1B, ab, lf1w, lf1b,
                                          P0sB, P1sB, PDB);
    fact2_kernel<<<6250, b256, 0, stream>>>(Mb01, d2_0B, P0sB, P1sB, PDB, colp,
                                            W2cB, lf2w, lf2b, f0B, f1hB);
    f2hop_kernel<<<391, b256, 0, stream>>>(f0B, f1hB, colp, aggrB);

    // ---- layer 1 (leaky fused into GEMM-A load & agg out) ----
    gemm128_lds<4, true, true, true><<<1563, b256, 0, stream>>>(bufA, Wt1 + 16384, labB64,
                                                                W2t + 8192, nullptr, 1, bufL);
    prep_sd<<<391, b256, 0, stream>>>(LPW + NN, degree, sdB);
    agg_xcd<<<25000, b256, 0, stream>>>(bufL, colp, sdB, degree,
                                        aggrB, 0.f, 1, bufA);

    // ---- output ----
    logits_mfma<<<782, b256, 0, stream>>>(bufA, Wb48, la2b, (float*)d_out);
}

// Round 11
// 431.691 us; speedup vs baseline: 1.1117x; 1.1117x over previous
//
#include <hip/hip_runtime.h>
#include <hip/hip_bf16.h>
#include <math.h>

#define NN 100000
#define NCLS 40
#define DEGC 16
#define NEDGE (NN*DEGC)
#define ALPHAC 0.2f
#define LPALPHA 0.5f

typedef short short8v __attribute__((ext_vector_type(8)));
typedef float f32x4 __attribute__((ext_vector_type(4)));

__device__ __forceinline__ short f2bf(float f) {
    unsigned u = __float_as_uint(f);
    u += 0x7fff + ((u >> 16) & 1);           // round-to-nearest-even
    return (short)(u >> 16);
}
__device__ __forceinline__ float bf2f(ushort u) {
    return __uint_as_float(((unsigned)u) << 16);
}

// ---------------------------------------------------------------------------
// MFMA GEMM (LDS-staged B, row-major C): C[NN][128](bf16) =
//   A1[NN][K1] @ B1t (+ labB64[NN][64] @ B2t) (+bias)
// ---------------------------------------------------------------------------
template <int NCH1, bool ABF, bool HASL>
__global__ __launch_bounds__(256) void gemm128_lds(
    const void* __restrict__ A1v, const ushort* __restrict__ B1t,
    const ushort* __restrict__ labB64, const ushort* __restrict__ B2t,
    const float* __restrict__ bias, int leakyA, ushort* __restrict__ C)
{
    constexpr int K1 = NCH1 * 32;
    constexpr int NG = NCH1 / 4;
    constexpr int NCH = NCH1 + (HASL ? 2 : 0);
    __shared__ __align__(16) ushort Bs1[128 * 128];
    __shared__ __align__(16) ushort Bs2[HASL ? 128 * 64 : 8];

    const int tid = threadIdx.x;
    const int l   = tid & 63;
    const int w   = tid >> 6;
    const int lr  = l & 15;
    const int lk8 = (l >> 4) << 3;
    const int n0  = blockIdx.x * 64 + w * 16;
    int r = n0 + lr; r = r < NN ? r : NN - 1;
    const int swz = (lr & 7) << 4;

    short8v afr[NCH];
    if (ABF) {
        const ushort* __restrict__ A = (const ushort*)A1v;
#pragma unroll
        for (int kc = 0; kc < NCH1; ++kc)
            afr[kc] = *(const short8v*)(A + (size_t)r * K1 + kc * 32 + lk8);
    } else {
        const float* __restrict__ A = (const float*)A1v;
#pragma unroll
        for (int g = 0; g < NCH1; g += 2) {
            const float* p0 = A + (size_t)r * K1 + g * 32 + lk8;
            const float* p1 = A + (size_t)r * K1 + (g + 1) * 32 + lk8;
            float4 a0 = *(const float4*)p0;
            float4 a1 = *(const float4*)(p0 + 4);
            float4 b0 = *(const float4*)p1;
            float4 b1 = *(const float4*)(p1 + 4);
            short8v va, vb;
            va[0] = f2bf(a0.x); va[1] = f2bf(a0.y); va[2] = f2bf(a0.z); va[3] = f2bf(a0.w);
            va[4] = f2bf(a1.x); va[5] = f2bf(a1.y); va[6] = f2bf(a1.z); va[7] = f2bf(a1.w);
            vb[0] = f2bf(b0.x); vb[1] = f2bf(b0.y); vb[2] = f2bf(b0.z); vb[3] = f2bf(b0.w);
            vb[4] = f2bf(b1.x); vb[5] = f2bf(b1.y); vb[6] = f2bf(b1.z); vb[7] = f2bf(b1.w);
            afr[g] = va;
            afr[g + 1] = vb;
        }
    }
    if (HASL) {
        afr[NCH1]     = *(const short8v*)(labB64 + (size_t)r * 64 + lk8);
        afr[NCH1 + 1] = *(const short8v*)(labB64 + (size_t)r * 64 + 32 + lk8);
    }
    if (ABF && leakyA) {
#pragma unroll
        for (int kc = 0; kc < NCH1; ++kc)
#pragma unroll
            for (int j = 0; j < 8; ++j) {
                float f = bf2f((ushort)afr[kc][j]);
                f = f > 0.f ? f : ALPHAC * f;
                afr[kc][j] = f2bf(f);
            }
    }

    if (HASL) {
#pragma unroll
        for (int s = 0; s < 4; ++s) {
            const int slot = tid + s * 256;
            const int row = slot >> 3, colq = slot & 7;
            uint4 v = *(const uint4*)(B2t + (size_t)row * 64 + colq * 8);
            *(uint4*)((char*)Bs2 + ((row * 128 + colq * 16) ^ ((row & 7) << 4))) = v;
        }
    }

    f32x4 acc[8];
#pragma unroll
    for (int ni = 0; ni < 8; ++ni) acc[ni] = (f32x4){0.f, 0.f, 0.f, 0.f};

#pragma unroll
    for (int g = 0; g < NG; ++g) {
        if (g) __syncthreads();
#pragma unroll
        for (int s = 0; s < 8; ++s) {
            const int slot = tid + s * 256;
            const int row = slot >> 4, colq = slot & 15;
            uint4 v = *(const uint4*)(B1t + (size_t)row * K1 + g * 128 + colq * 8);
            *(uint4*)((char*)Bs1 + ((row * 256 + colq * 16) ^ ((row & 7) << 4))) = v;
        }
        __syncthreads();
#pragma unroll
        for (int ni = 0; ni < 8; ++ni) {
#pragma unroll
            for (int kc = 0; kc < 4; ++kc) {
                short8v b = *(const short8v*)((const char*)Bs1 +
                    (((ni * 16 + lr) * 256 + kc * 64 + lk8 * 2) ^ swz));
                acc[ni] = __builtin_amdgcn_mfma_f32_16x16x32_bf16(afr[g * 4 + kc], b, acc[ni], 0, 0, 0);
            }
        }
    }
    if (HASL) {
#pragma unroll
        for (int ni = 0; ni < 8; ++ni) {
#pragma unroll
            for (int kc = 0; kc < 2; ++kc) {
                short8v b = *(const short8v*)((const char*)Bs2 +
                    (((ni * 16 + lr) * 128 + kc * 64 + lk8 * 2) ^ swz));
                acc[ni] = __builtin_amdgcn_mfma_f32_16x16x32_bf16(afr[NCH1 + kc], b, acc[ni], 0, 0, 0);
            }
        }
    }

    const int rsub = (l >> 4) << 2;
#pragma unroll
    for (int ni = 0; ni < 8; ++ni) {
        const int cc = ni * 16 + lr;
        const float bv = bias ? bias[cc] : 0.f;
#pragma unroll
        for (int rg = 0; rg < 4; ++rg) {
            const int rr = n0 + rsub + rg;
            if (rr < NN) C[(size_t)rr * 128 + cc] = (ushort)f2bf(acc[ni][rg] + bv);
        }
    }
}

// ---------------------------------------------------------------------------
// Aggregation v3 (wide gathers): one wave per node.  Each gather instruction
// loads uint4/lane: 16 lanes x 16B = one 256B row, 4 rows per instruction ->
// 4 addresses per row instead of 16 (TA address-rate is the bottleneck).
// Cross-subgroup reduce via shfl_xor(16,32); q==0 lanes store the row.
// ---------------------------------------------------------------------------
__global__ __launch_bounds__(256) void agg_v3(
    const ushort* __restrict__ hlin, const int* __restrict__ col,
    const float* __restrict__ sd, const float* __restrict__ degree,
    const float* __restrict__ aggrv, const float aggrs, int do_leaky,
    ushort* __restrict__ hout)
{
    const int lane = threadIdx.x & 63;
    const int node = blockIdx.x * 4 + (threadIdx.x >> 6);
    const int q  = lane >> 4;        // row-subgroup 0..3
    const int cq = lane & 15;        // 16B column-quarter

    int cl = 0; float sl = 0.f;
    if (lane < 16) {
        cl = col[node * 16 + lane];
        sl = sd[cl];
    }

    float ax[8];
#pragma unroll
    for (int s = 0; s < 8; ++s) ax[s] = 0.f;

#pragma unroll
    for (int g = 0; g < 4; ++g) {
        const int nb = g * 4 + q;
        const int   c  = __shfl(cl, nb, 64);
        const float wv = __shfl(sl, nb, 64);
        const uint4 u = *(const uint4*)(hlin + (size_t)c * 128 + cq * 8);
        const unsigned uu[4] = {u.x, u.y, u.z, u.w};
#pragma unroll
        for (int s = 0; s < 4; ++s) {
            ax[s * 2]     += wv * bf2f((ushort)(uu[s] & 0xffff));
            ax[s * 2 + 1] += wv * bf2f((ushort)(uu[s] >> 16));
        }
    }
    // reduce over q (bits 4,5 of lane)
#pragma unroll
    for (int s = 0; s < 8; ++s) {
        ax[s] += __shfl_xor(ax[s], 16, 64);
        ax[s] += __shfl_xor(ax[s], 32, 64);
    }

    const uint4 us = *(const uint4*)(hlin + (size_t)node * 128 + cq * 8);
    const unsigned uus[4] = {us.x, us.y, us.z, us.w};
    const float a = aggrv ? aggrv[node] : aggrs;
    const float d = degree[node];
    uint4 uo;
    unsigned* uop = &uo.x;
#pragma unroll
    for (int s = 0; s < 4; ++s) {
        float ox = a * ax[s * 2]     * d + (1.f - a) * bf2f((ushort)(uus[s] & 0xffff));
        float oy = a * ax[s * 2 + 1] * d + (1.f - a) * bf2f((ushort)(uus[s] >> 16));
        if (do_leaky) {
            ox = ox > 0.f ? ox : ALPHAC * ox;
            oy = oy > 0.f ? oy : ALPHAC * oy;
        }
        uop[s] = (unsigned)(ushort)f2bf(ox) | ((unsigned)(ushort)f2bf(oy) << 16);
    }
    if (q == 0)
        *(uint4*)(hout + (size_t)node * 128 + cq * 8) = uo;
}

__global__ void prep_sd(const float* __restrict__ lpw, const float* __restrict__ degree,
                        float* __restrict__ sd)
{
    int i = blockIdx.x * 256 + threadIdx.x;
    if (i < NN) sd[i] = lpw[i] * degree[i];
}

// ---------------------------------------------------------------------------
// Small MFMA GEMM (LDS-staged W) writing packed Mb01[N][32] (m0@0, m1@16).
// ---------------------------------------------------------------------------
__global__ __launch_bounds__(256) void gemm16_mfma(
    const ushort* __restrict__ A, const ushort* __restrict__ Wb,
    const float* __restrict__ bias, ushort* __restrict__ Mout, int ooff)
{
    __shared__ __align__(16) ushort Wl[16 * 128];
    const int tid = threadIdx.x;
    const int l  = tid & 63;
    const int w  = tid >> 6;
    const int lr = l & 15;
    const int lk = (l >> 4) << 3;
    const int swz = (lr & 7) << 4;
    {
        const int row = tid >> 4, colq = tid & 15;
        uint4 v = *(const uint4*)(Wb + (size_t)row * 128 + colq * 8);
        *(uint4*)((char*)Wl + ((row * 256 + colq * 16) ^ ((row & 7) << 4))) = v;
    }
    const int n0 = blockIdx.x * 64 + w * 16;
    int ar = n0 + lr; ar = ar < NN ? ar : NN - 1;
    short8v a[4];
#pragma unroll
    for (int kc = 0; kc < 4; ++kc)
        a[kc] = *(const short8v*)(A + (size_t)ar * 128 + kc * 32 + lk);
    __syncthreads();
    f32x4 acc = (f32x4){0.f, 0.f, 0.f, 0.f};
#pragma unroll
    for (int kc = 0; kc < 4; ++kc) {
        short8v b = *(const short8v*)((const char*)Wl + ((lr * 256 + kc * 64 + lk * 2) ^ swz));
        acc = __builtin_amdgcn_mfma_f32_16x16x32_bf16(a[kc], b, acc, 0, 0, 0);
    }
    const float bv = bias[lr];
    const int rb = n0 + ((l >> 4) << 2);
#pragma unroll
    for (int r = 0; r < 4; ++r) {
        int rr = rb + r;
        if (rr < NN) Mout[(size_t)rr * 32 + ooff + lr] = (ushort)f2bf(acc[r] + bv);
    }
}

// ---------------------------------------------------------------------------
// Fused dual mini(): one 64 B gather serves both m0 and m1 distances.
// ---------------------------------------------------------------------------
__global__ __launch_bounds__(256) void mini2_dual(
    const ushort* __restrict__ Mb01, const int* __restrict__ col,
    float* __restrict__ d2_0, float* __restrict__ d2_1)
{
    __shared__ float sm0[16][16][17];
    __shared__ float sm1[16][16][17];
    __shared__ float av0[16][16];
    __shared__ float av1[16][16];
    const int tid = threadIdx.x;
    const int g = tid >> 4, j = tid & 15;
    const int node = blockIdx.x * 16 + g;
    const int c = col[node * 16 + j];
    const ushort* __restrict__ rowp = Mb01 + (size_t)c * 32;
    const uint4 u0 = *(const uint4*)rowp;
    const uint4 u1 = *(const uint4*)(rowp + 8);
    const uint4 u2 = *(const uint4*)(rowp + 16);
    const uint4 u3 = *(const uint4*)(rowp + 24);
    const unsigned w0[8] = {u0.x, u0.y, u0.z, u0.w, u1.x, u1.y, u1.z, u1.w};
    const unsigned w1[8] = {u2.x, u2.y, u2.z, u2.w, u3.x, u3.y, u3.z, u3.w};
#pragma unroll
    for (int s = 0; s < 8; ++s) {
        sm0[g][j][s * 2]     = bf2f((ushort)(w0[s] & 0xffff));
        sm0[g][j][s * 2 + 1] = bf2f((ushort)(w0[s] >> 16));
        sm1[g][j][s * 2]     = bf2f((ushort)(w1[s] & 0xffff));
        sm1[g][j][s * 2 + 1] = bf2f((ushort)(w1[s] >> 16));
    }
    __syncthreads();
    float a0 = 0.f, a1 = 0.f;
#pragma unroll
    for (int nb = 0; nb < 16; ++nb) { a0 += sm0[g][nb][j]; a1 += sm1[g][nb][j]; }
    av0[g][j] = a0 * (1.f / 16.f);
    av1[g][j] = a1 * (1.f / 16.f);
    __syncthreads();
    float dd0 = 1e-12f, dd1 = 1e-12f;
#pragma unroll
    for (int d = 0; d < 16; ++d) {
        float t0 = av0[g][d] - sm0[g][j][d];
        float t1 = av1[g][d] - sm1[g][j][d];
        dd0 += t0 * t0;
        dd1 += t1 * t1;
    }
    float dist0 = sqrtf(dd0), dist1 = sqrtf(dd1);
#pragma unroll
    for (int off = 1; off < 16; off <<= 1) {
        dist0 += __shfl_xor(dist0, off, 64);
        dist1 += __shfl_xor(dist1, off, 64);
    }
    if (j == 0) {
        d2_0[node] = dist0 * (1.f / 16.f);
        d2_1[node] = dist1 * (1.f / 16.f);
    }
}

// ---------------------------------------------------------------------------
// Per-node factor precompute (reads packed Mb01).
// ---------------------------------------------------------------------------
__global__ __launch_bounds__(256) void prep_pnode(
    const ushort* __restrict__ Mb01, const float* __restrict__ d2_0,
    const float* __restrict__ d2_1,
    const float* __restrict__ ab, const float* __restrict__ lf1w,
    const float* __restrict__ lf1b,
    float* __restrict__ P0s, float* __restrict__ P1s, ushort* __restrict__ PD)
{
    const int idx = blockIdx.x * 256 + threadIdx.x;
    const int i = idx >> 4, k = idx & 15;
    float m0[17], m1a[17];
    const ushort* r0 = Mb01 + (size_t)i * 32;
    const ushort* r1 = r0 + 16;
#pragma unroll
    for (int d = 0; d < 16; ++d) {
        m0[d]  = bf2f(r0[d]);
        m1a[d] = bf2f(r1[d]) + ab[d];
    }
    m0[16]  = d2_0[i];
    m1a[16] = d2_1[i] + ab[16];
    const float* __restrict__ Wk = lf1w + k * 51;
    float p0s = lf1b[k], p1s = p0s, p0d = 0.f, p1d = 0.f;
#pragma unroll
    for (int d = 0; d < 17; ++d) {
        const float w0 = Wk[d], w1 = Wk[17 + d];
        p0s += m0[d]  * w0;  p0d += m0[d]  * w1;
        p1s += m1a[d] * w0;  p1d += m1a[d] * w1;
    }
    P0s[idx] = p0s;
    P1s[idx] = p1s;
    PD[(size_t)i * 32 + k]      = (ushort)f2bf(p0d);
    PD[(size_t)i * 32 + 16 + k] = (ushort)f2bf(p1d);
}

// ---------------------------------------------------------------------------
// Edge factors (m0 from packed Mb01, stride 32); fused f1hop.
// ---------------------------------------------------------------------------
__global__ __launch_bounds__(256) void fact2_kernel(
    const ushort* __restrict__ Mb01, const float* __restrict__ d2_0,
    const float* __restrict__ P0s, const float* __restrict__ P1s,
    const ushort* __restrict__ PD, const int* __restrict__ col,
    const float* __restrict__ W2c, const float* __restrict__ lf2w,
    const float* __restrict__ lf2b,
    float* __restrict__ f0out, float* __restrict__ f1hout)
{
    const int e = blockIdx.x * 256 + threadIdx.x;
    const int i = e >> 4;
    const int c = col[e];

    const uint4 ui0 = *(const uint4*)(Mb01 + (size_t)i * 32);
    const uint4 ui1 = *(const uint4*)(Mb01 + (size_t)i * 32 + 8);
    const uint4 uc0 = *(const uint4*)(Mb01 + (size_t)c * 32);
    const uint4 uc1 = *(const uint4*)(Mb01 + (size_t)c * 32 + 8);
    const unsigned wi[8] = {ui0.x, ui0.y, ui0.z, ui0.w, ui1.x, ui1.y, ui1.z, ui1.w};
    const unsigned wc[8] = {uc0.x, uc0.y, uc0.z, uc0.w, uc1.x, uc1.y, uc1.z, uc1.w};

    float H[16];
#pragma unroll
    for (int k = 0; k < 16; ++k) H[k] = 0.f;
#pragma unroll
    for (int s = 0; s < 8; ++s) {
        const float hd0 = fabsf(bf2f((ushort)(wc[s] & 0xffff)) - bf2f((ushort)(wi[s] & 0xffff)));
        const float hd1 = fabsf(bf2f((ushort)(wc[s] >> 16))    - bf2f((ushort)(wi[s] >> 16)));
        const float* __restrict__ w0 = W2c + (s * 2) * 16;
        const float* __restrict__ w1 = W2c + (s * 2 + 1) * 16;
#pragma unroll
        for (int k = 0; k < 16; ++k) H[k] += hd0 * w0[k] + hd1 * w1[k];
    }
    {
        const float hdd = fabsf(d2_0[c] - d2_0[i]);
        const float* __restrict__ w = W2c + 16 * 16;
#pragma unroll
        for (int k = 0; k < 16; ++k) H[k] += hdd * w[k];
    }

    const float* __restrict__ p0 = P0s + (size_t)i * 16;
    const float* __restrict__ p1 = P1s + (size_t)i * 16;
    const ushort* __restrict__ pd = PD + (size_t)c * 32;
    const uint4 pd0 = *(const uint4*)pd;
    const uint4 pd1 = *(const uint4*)(pd + 8);
    const uint4 pd2 = *(const uint4*)(pd + 16);
    const uint4 pd3 = *(const uint4*)(pd + 24);
    const unsigned pdu[16] = {pd0.x, pd0.y, pd0.z, pd0.w, pd1.x, pd1.y, pd1.z, pd1.w,
                              pd2.x, pd2.y, pd2.z, pd2.w, pd3.x, pd3.y, pd3.z, pd3.w};
    float P0d[16], P1d[16];
#pragma unroll
    for (int s = 0; s < 8; ++s) {
        P0d[s * 2]     = bf2f((ushort)(pdu[s] & 0xffff));
        P0d[s * 2 + 1] = bf2f((ushort)(pdu[s] >> 16));
        P1d[s * 2]     = bf2f((ushort)(pdu[8 + s] & 0xffff));
        P1d[s * 2 + 1] = bf2f((ushort)(pdu[8 + s] >> 16));
    }
    float a0 = lf2b[0], a1 = a0;
#pragma unroll
    for (int k = 0; k < 16; ++k) {
        const float t0 = p0[k] + P0d[k] + H[k];
        const float t1 = p1[k] + P1d[k] + H[k];
        const float lw = lf2w[k];
        a0 += (1.f - 2.f / (__expf(2.f * t0) + 1.f)) * lw;
        a1 += (1.f - 2.f / (__expf(2.f * t1) + 1.f)) * lw;
    }
    f0out[e] = 1.f / (1.f + __expf(-a0));
    float f1 = 1.f / (1.f + __expf(-a1));
#pragma unroll
    for (int off = 1; off < 16; off <<= 1) f1 += __shfl_xor(f1, off, 64);
    if ((threadIdx.x & 15) == 0) f1hout[i] = f1 * (1.f / 16.f);
}

__global__ void f2hop_kernel(const float* __restrict__ f0, const float* __restrict__ f1h,
                             const int* __restrict__ col, float* __restrict__ out)
{
    const int i = blockIdx.x * 256 + threadIdx.x;
    if (i >= NN) return;
    float s = 0.f;
#pragma unroll
    for (int t = 0; t < 16; ++t) {
        int e = i * 16 + t;
        s += f0[e] * f1h[col[e]];
    }
    out[i] = s * (1.f / 16.f);
}

// ---------------------------------------------------------------------------
// MFMA logits + fused log_softmax (LDS-staged W).
// ---------------------------------------------------------------------------
__global__ __launch_bounds__(256) void logits_mfma(
    const ushort* __restrict__ X, const ushort* __restrict__ Wb48,
    const float* __restrict__ bias, float* __restrict__ out)
{
    __shared__ __align__(16) ushort Wl[48 * 128];
    const int tid = threadIdx.x;
    const int l  = tid & 63;
    const int w  = tid >> 6;
    const int lr = l & 15;
    const int lk = (l >> 4) << 3;
    const int swz = (lr & 7) << 4;
#pragma unroll
    for (int s = 0; s < 6; ++s) {
        const int slot = tid + s * 256;
        const int row = slot >> 4, colq = slot & 15;
        uint4 v = *(const uint4*)(Wb48 + (size_t)row * 128 + colq * 8);
        *(uint4*)((char*)Wl + ((row * 256 + colq * 16) ^ ((row & 7) << 4))) = v;
    }
    const int row_base = blockIdx.x * 128 + w * 32;
    short8v afr[2][4];
#pragma unroll
    for (int mi = 0; mi < 2; ++mi) {
        int r = row_base + mi * 16 + lr;
        r = r < NN ? r : NN - 1;
#pragma unroll
        for (int kc = 0; kc < 4; ++kc)
            afr[mi][kc] = *(const short8v*)(X + (size_t)r * 128 + kc * 32 + lk);
    }
    __syncthreads();
    f32x4 acc[2][3];
#pragma unroll
    for (int mi = 0; mi < 2; ++mi)
#pragma unroll
        for (int ni = 0; ni < 3; ++ni) acc[mi][ni] = (f32x4){0.f, 0.f, 0.f, 0.f};
#pragma unroll
    for (int ni = 0; ni < 3; ++ni) {
#pragma unroll
        for (int kc = 0; kc < 4; ++kc) {
            short8v b = *(const short8v*)((const char*)Wl +
                (((ni * 16 + lr) * 256 + kc * 64 + lk * 2) ^ swz));
#pragma unroll
            for (int mi = 0; mi < 2; ++mi)
                acc[mi][ni] = __builtin_amdgcn_mfma_f32_16x16x32_bf16(afr[mi][kc], b, acc[mi][ni], 0, 0, 0);
        }
    }

    const float b0 = bias[lr];
    const float b1 = bias[16 + lr];
    const float b2 = (lr < 8) ? bias[32 + lr] : 0.f;
    const int rsub = (l >> 4) << 2;
#pragma unroll
    for (int mi = 0; mi < 2; ++mi) {
#pragma unroll
        for (int reg = 0; reg < 4; ++reg) {
            const int row = row_base + mi * 16 + rsub + reg;
            const float z0 = acc[mi][0][reg] + b0;
            const float z1 = acc[mi][1][reg] + b1;
            const float z2 = (lr < 8) ? acc[mi][2][reg] + b2 : -1e30f;
            float m = fmaxf(fmaxf(z0, z1), z2);
#pragma unroll
            for (int off = 1; off < 16; off <<= 1) m = fmaxf(m, __shfl_xor(m, off, 64));
            float s = __expf(z0 - m) + __expf(z1 - m) + ((lr < 8) ? __expf(z2 - m) : 0.f);
#pragma unroll
            for (int off = 1; off < 16; off <<= 1) s += __shfl_xor(s, off, 64);
            const float lg = m + __logf(s);
            if (row < NN) {
                float* __restrict__ po = out + (size_t)row * NCLS;
                po[lr] = z0 - lg;
                po[16 + lr] = z1 - lg;
                if (lr < 8) po[32 + lr] = z2 - lg;
            }
        }
    }
}

// ---------------------------------------------------------------------------
// Prep kernels
// ---------------------------------------------------------------------------
__global__ void cvt_bf16(const float* __restrict__ src, ushort* __restrict__ dst, int n)
{
    int i = blockIdx.x * 256 + threadIdx.x;
    if (i < n) dst[i] = (ushort)f2bf(src[i]);
}

__global__ void cvt_label64(const float* __restrict__ label, ushort* __restrict__ labB64)
{
    int idx = blockIdx.x * 256 + threadIdx.x;
    int i = idx >> 6, c = idx & 63;
    labB64[idx] = (c < NCLS) ? (ushort)f2bf(label[(size_t)i * NCLS + c]) : (ushort)0;
}

__global__ void prep_wt1(const float* __restrict__ Ws, ushort* __restrict__ Wt1)
{
    int i = blockIdx.x * 256 + threadIdx.x;
    int ll = i >> 14, r = i & 16383;
    int m = r >> 7, k = r & 127;
    Wt1[i] = (ushort)f2bf(Ws[(size_t)ll * 32768 + k * 128 + m]);
}

__global__ void prep_w2t(const float* __restrict__ L2F, const float* __restrict__ Ws,
                         ushort* __restrict__ W2t)
{
    int i = blockIdx.x * 256 + threadIdx.x;
    int ll = i >> 13, r = i & 8191;
    int m = r >> 6, c = r & 63;
    float acc = 0.f;
    if (c < NCLS) {
        const float* Wl = Ws + (size_t)ll * 32768 + 128 * 128;
        for (int j = 0; j < 128; ++j) acc += L2F[c * 128 + j] * Wl[j * 128 + m];
    }
    W2t[i] = (ushort)f2bf(acc);
}

__global__ void prep_wb48(const float* __restrict__ la2w, ushort* __restrict__ Wb48)
{
    int i = blockIdx.x * 256 + threadIdx.x;
    if (i >= 48 * 128) return;
    int c = i >> 7;
    Wb48[i] = (c < NCLS) ? (ushort)f2bf(la2w[i]) : (ushort)0;
}

__global__ void prep_w2c(const float* __restrict__ lf1w, float* __restrict__ W2c)
{
    int t = blockIdx.x * 256 + threadIdx.x;
    if (t < 272) {
        int d = t >> 4, k = t & 15;
        W2c[t] = lf1w[k * 51 + 34 + d];
    }
}

// ---------------------------------------------------------------------------
extern "C" void kernel_launch(void* const* d_in, const int* in_sizes, int n_in,
                              void* d_out, int out_size, void* d_ws, size_t ws_size,
                              hipStream_t stream)
{
    const float* x      = (const float*)d_in[0];
    const int*   edges  = (const int*)d_in[1];
    const float* degree = (const float*)d_in[2];
    const float* label  = (const float*)d_in[4];
    const float* lb_w   = (const float*)d_in[5];
    const float* lb_b   = (const float*)d_in[6];
    const float* L2F    = (const float*)d_in[7];
    const float* Ws     = (const float*)d_in[8];
    const float* w2m    = (const float*)d_in[9];
    const float* b2m    = (const float*)d_in[10];
    const float* ab     = (const float*)d_in[11];
    const float* lf1w   = (const float*)d_in[12];
    const float* lf1b   = (const float*)d_in[13];
    const float* lf2w   = (const float*)d_in[14];
    const float* lf2b   = (const float*)d_in[15];
    const float* LPW    = (const float*)d_in[16];
    const float* la2w   = (const float*)d_in[17];
    const float* la2b   = (const float*)d_in[18];
    const int* colp = edges + NEDGE;

    float* ws = (float*)d_ws;
    size_t o = 0;
    float* d2_0B = ws + o; o += NN;
    float* d2_1B = ws + o; o += NN;
    float* P0sB  = ws + o; o += (size_t)NN * 16;
    float* P1sB  = ws + o; o += (size_t)NN * 16;
    float* f0B   = ws + o; o += NEDGE;
    float* f1hB  = ws + o; o += NN;
    float* aggrB = ws + o; o += NN;
    float* sdB   = ws + o; o += NN;
    float* W2cB  = ws + o; o += 272;
    ushort* bufA = (ushort*)(ws + o); o += (size_t)NN * 128 / 2;
    ushort* bufL = (ushort*)(ws + o); o += (size_t)NN * 128 / 2;
    ushort* labB64 = (ushort*)(ws + o); o += (size_t)NN * 64 / 2;
    ushort* Mb01 = (ushort*)(ws + o); o += (size_t)NN * 32 / 2;
    ushort* PDB  = (ushort*)(ws + o); o += (size_t)NN * 32 / 2;
    ushort* Bt0  = (ushort*)(ws + o); o += 128 * 256 / 2;
    ushort* Wt1  = (ushort*)(ws + o); o += 2 * 128 * 128 / 2;
    ushort* W2t  = (ushort*)(ws + o); o += 2 * 128 * 64 / 2;
    ushort* W2mB = (ushort*)(ws + o); o += 16 * 128 / 2;
    ushort* Wb48 = (ushort*)(ws + o); o += 48 * 128 / 2;

    dim3 b256(256);
    // prep
    cvt_bf16<<<128, b256, 0, stream>>>(lb_w, Bt0, 128 * 256);
    prep_wt1<<<128, b256, 0, stream>>>(Ws, Wt1);
    prep_w2t<<<64, b256, 0, stream>>>(L2F, Ws, W2t);
    prep_wb48<<<24, b256, 0, stream>>>(la2w, Wb48);
    prep_w2c<<<2, b256, 0, stream>>>(lf1w, W2cB);
    cvt_bf16<<<8, b256, 0, stream>>>(w2m, W2mB, 16 * 128);
    cvt_label64<<<25000, b256, 0, stream>>>(label, labB64);

    // h0 = x @ lb_w^T + lb_b   (A f32, K=256)
    gemm128_lds<8, false, false><<<1563, b256, 0, stream>>>(x, Bt0, nullptr, nullptr,
                                                            lb_b, 0, bufA);

    // ---- layer 0 ----
    gemm128_lds<4, true, true><<<1563, b256, 0, stream>>>(bufA, Wt1, labB64, W2t,
                                                          nullptr, 0, bufL);
    gemm16_mfma<<<1563, b256, 0, stream>>>(bufA, W2mB, b2m, Mb01, 16);   // m1 = mini(h0)
    prep_sd<<<391, b256, 0, stream>>>(LPW, degree, sdB);
    agg_v3<<<25000, b256, 0, stream>>>(bufL, colp, sdB, degree,
                                       nullptr, LPALPHA, 0, bufA);
    gemm16_mfma<<<1563, b256, 0, stream>>>(bufA, W2mB, b2m, Mb01, 0);    // m0 = mini(h)
    mini2_dual<<<6250, b256, 0, stream>>>(Mb01, colp, d2_0B, d2_1B);
    prep_pnode<<<6250, b256, 0, stream>>>(Mb01, d2_0B, d2_1B, ab, lf1w, lf1b,
                                          P0sB, P1sB, PDB);
    fact2_kernel<<<6250, b256, 0, stream>>>(Mb01, d2_0B, P0sB, P1sB, PDB, colp,
                                            W2cB, lf2w, lf2b, f0B, f1hB);
    f2hop_kernel<<<391, b256, 0, stream>>>(f0B, f1hB, colp, aggrB);

    // ---- layer 1 (leaky fused into GEMM-A load & agg out) ----
    gemm128_lds<4, true, true><<<1563, b256, 0, stream>>>(bufA, Wt1 + 16384, labB64,
                                                          W2t + 8192, nullptr, 1, bufL);
    prep_sd<<<391, b256, 0, stream>>>(LPW + NN, degree, sdB);
    agg_v3<<<25000, b256, 0, stream>>>(bufL, colp, sdB, degree,
                                       aggrB, 0.f, 1, bufA);

    // ---- output ----
    logits_mfma<<<782, b256, 0, stream>>>(bufA, Wb48, la2b, (float*)d_out);
}